// Round 5
// baseline (140.076 us; speedup 1.0000x reference)
//
#include <hip/hip_runtime.h>

#define NG 512
#define NPX 262144
#define GRID1D 32
#define NCELL (GRID1D * GRID1D)   // 1024 cells
#define CELLCAP 512               // mean 256, sigma 16 -> 16 sigma headroom
#define KSCALE 0.72134752044448170368f   /* 0.5 * log2(e) */
#define WCULL  -30.0f             /* dropped term < 2^-30; x512 < 5e-7 */

typedef float v2f __attribute__((ext_vector_type(2)));

// d_ws layout:
//   [0, 4096)                 : int cursors[NCELL]        (memset to 0 each call)
//   [4096, 4096+4MB)          : float2 sorted_xy[NCELL*CELLCAP]
//   [4096+4MB, +2MB)          : int    sorted_idx[NCELL*CELLCAP]

// ---------------- pass 1: spatial binning of pixels ----------------
__global__ __launch_bounds__(256)
void bin_kernel(const float* __restrict__ x, int* __restrict__ cur,
                float2* __restrict__ sxy, int* __restrict__ sidx)
{
    int tid = blockIdx.x * 256 + threadIdx.x;
    float2 p = ((const float2*)x)[tid];
    int cx = min((int)(p.x * GRID1D), GRID1D - 1);
    int cy = min((int)(p.y * GRID1D), GRID1D - 1);
    int cell = cy * GRID1D + cx;
    int pos = atomicAdd(&cur[cell], 1);
    if (pos < CELLCAP) {
        sxy[cell * CELLCAP + pos] = p;
        sidx[cell * CELLCAP + pos] = tid;
    }
}

// ---------------- pass 2: per-cell cull + splat ----------------
struct GPair {   // two Gaussians interleaved for packed-f32 math (48 B)
    v2f p00, p01, nu, p11, nv, l2a;
};

__device__ inline v2f pair_term(const GPair& g, float X, float Y) {
    // w = l2a - u^2 - v^2 ; term = 2^w  (alpha and 0.5*log2e folded in)
    v2f u = g.p00 * X + g.p01 * Y + g.nu;
    v2f v = g.p11 * Y + g.nv;
    v2f w = g.l2a - u * u - v * v;
    v2f e;
    e.x = __builtin_amdgcn_exp2f(w.x);
    e.y = __builtin_amdgcn_exp2f(w.y);
    return e;
}

__global__ __launch_bounds__(128, 4)
void splat_kernel(const int* __restrict__ cur,
                  const float2* __restrict__ sxy,
                  const int* __restrict__ sidx,
                  const float* __restrict__ alphas,
                  const float* __restrict__ means,
                  const float* __restrict__ rotations,
                  const float* __restrict__ scales,
                  float* __restrict__ out)
{
    __shared__ GPair gp[(NG / 2) + 8];
    __shared__ int nkept;

    int tid  = threadIdx.x;
    int cell = blockIdx.x >> 1;   // two sub-blocks per cell (redundant cull)
    int sub  = blockIdx.x & 1;
    int cx = cell & (GRID1D - 1);
    int cy = cell >> 5;
    float bx0 = cx * (1.0f / GRID1D), bx1 = bx0 + (1.0f / GRID1D);
    float by0 = cy * (1.0f / GRID1D), by1 = by0 + (1.0f / GRID1D);

    if (tid == 0) nkept = 0;
    __syncthreads();

    // cull 512 Gaussians against the cell box; compact survivors into LDS
    for (int n = tid; n < NG; n += 128) {
        float rot = rotations[n];
        float sth, cth;
        sincosf(rot, &sth, &cth);
        float s0 = scales[2 * n + 0];
        float s1 = scales[2 * n + 1];
        float r00 = s0 * cth, r01 = -s1 * sth;
        float r10 = s0 * sth, r11 =  s1 * cth;
        float Ar = r00 * r00 + r01 * r01;
        float Br = r00 * r10 + r01 * r11;
        float Dr = r10 * r10 + r11 * r11;
        float det = Ar * Dr - Br * Br;
        float kc00 =  KSCALE * Dr / det;
        float kc01 = -KSCALE * Br / det;
        float p00 = sqrtf(kc00);
        float p01 = kc01 / p00;
        float p11 = sqrtf(KSCALE / Dr);   // exact: kc11 - kc01^2/kc00 = KSCALE/Dr
        float mx = means[2 * n + 0];
        float my = means[2 * n + 1];
        float nu = -(p00 * mx + p01 * my);
        float nv = -(p11 * my);
        float l2a = log2f(alphas[n]);

        // conservative max of w over the cell box (u,v linear in x,y; p00,p11 > 0)
        float py0 = p01 * by0, py1 = p01 * by1;
        float umin = p00 * bx0 + fminf(py0, py1) + nu;
        float umax = p00 * bx1 + fmaxf(py0, py1) + nu;
        float vmin = p11 * by0 + nv;
        float vmax = p11 * by1 + nv;
        float du = (umin > 0.0f) ? umin : ((umax < 0.0f) ? umax : 0.0f);
        float dv = (vmin > 0.0f) ? vmin : ((vmax < 0.0f) ? vmax : 0.0f);
        float wmax = l2a - du * du - dv * dv;

        if (wmax > WCULL) {
            int slot = atomicAdd(&nkept, 1);
            int pr = slot >> 1, h = slot & 1;
            gp[pr].p00[h] = p00; gp[pr].p01[h] = p01; gp[pr].nu[h]  = nu;
            gp[pr].p11[h] = p11; gp[pr].nv[h]  = nv;  gp[pr].l2a[h] = l2a;
        }
    }
    __syncthreads();

    int nk = nkept;
    int nround = (nk + 7) & ~7;          // pad to multiple of 8 Gaussians (4 pairs)
    if (tid < nround - nk) {
        int slot = nk + tid;
        int pr = slot >> 1, h = slot & 1;
        gp[pr].p00[h] = 0.0f; gp[pr].p01[h] = 0.0f; gp[pr].nu[h]  = 0.0f;
        gp[pr].p11[h] = 0.0f; gp[pr].nv[h]  = 0.0f; gp[pr].l2a[h] = -10000.0f; // 2^w -> 0
    }
    __syncthreads();
    int npairs = nround >> 1;

    int count = min(cur[cell], CELLCAP);
    const float4* pxy = (const float4*)(sxy + cell * CELLCAP);
    const int*    idx = sidx + cell * CELLCAP;

    // each thread: one pixel PAIR (2 px), sub-blocks interleave pair indices
    for (int p0 = tid + sub * 128; 2 * p0 < count; p0 += 256) {
        float4 pv = pxy[p0];               // 2 pixels' (x,y)
        float xa = pv.x, ya = pv.y;
        float xb = pv.z, yb = pv.w;
        v2f accA = {0.0f, 0.0f}, accB = {0.0f, 0.0f};

        for (int t = 0; t < npairs; t += 4) {
            GPair g0 = gp[t + 0];          // 3x ds_read_b128 each, batched
            GPair g1 = gp[t + 1];
            GPair g2 = gp[t + 2];
            GPair g3 = gp[t + 3];
            accA += pair_term(g0, xa, ya);  accB += pair_term(g0, xb, yb);
            accA += pair_term(g1, xa, ya);  accB += pair_term(g1, xb, yb);
            accA += pair_term(g2, xa, ya);  accB += pair_term(g2, xb, yb);
            accA += pair_term(g3, xa, ya);  accB += pair_term(g3, xb, yb);
        }

        out[idx[2 * p0]] = accA.x + accA.y;
        if (2 * p0 + 1 < count)
            out[idx[2 * p0 + 1]] = accB.x + accB.y;
    }
}

extern "C" void kernel_launch(void* const* d_in, const int* in_sizes, int n_in,
                              void* d_out, int out_size, void* d_ws, size_t ws_size,
                              hipStream_t stream) {
    const float* x         = (const float*)d_in[0];
    const float* alphas    = (const float*)d_in[1];
    const float* means     = (const float*)d_in[2];
    const float* rotations = (const float*)d_in[3];
    const float* scales    = (const float*)d_in[4];
    float* out = (float*)d_out;

    char* ws = (char*)d_ws;
    int*    cur  = (int*)ws;
    float2* sxy  = (float2*)(ws + 4096);
    int*    sidx = (int*)(ws + 4096 + (size_t)NCELL * CELLCAP * sizeof(float2));

    hipMemsetAsync(cur, 0, NCELL * sizeof(int), stream);
    bin_kernel<<<NPX / 256, 256, 0, stream>>>(x, cur, sxy, sidx);
    splat_kernel<<<NCELL * 2, 128, 0, stream>>>(cur, sxy, sidx,
                                                alphas, means, rotations, scales, out);
}

// Round 6
// 101.077 us; speedup vs baseline: 1.3858x; 1.3858x over previous
//
#include <hip/hip_runtime.h>

#define NG 512
#define NPX 262144
#define GRID1D 32
#define NCELL (GRID1D * GRID1D)   // 1024 cells
#define NSEG 8                    // cursor segments (contention / NSEG)
#define SEGCAP 72                 // mean 32/segcell; P(Poisson(32)>71) ~ 1e-9
#define PXCAP 448                 // mean 256/cell; ~12 sigma headroom
#define KSCALE 0.72134752044448170368f   /* 0.5 * log2(e) */
#define WCULL  -30.0f             /* dropped term < 2^-30; x512 < 5e-7 */

typedef float v2f __attribute__((ext_vector_type(2)));

// d_ws layout:
//   [0, 32768)        : int cursors[NSEG][NCELL]   (memset 0 each call)
//   [32768, +9.44MB)  : float4 entries[NSEG][NCELL][SEGCAP] = (x, y, idx_bits, 0)

// ---------------- pass 1: segmented spatial binning ----------------
__global__ __launch_bounds__(256)
void bin_kernel(const float* __restrict__ x, int* __restrict__ cur,
                float4* __restrict__ entries)
{
    int t = blockIdx.x * 256 + threadIdx.x;       // 0..131071, 2 pixels each
    float4 p2 = ((const float4*)x)[t];
    int seg = blockIdx.x & (NSEG - 1);

    int cxa = min((int)(p2.x * GRID1D), GRID1D - 1);
    int cya = min((int)(p2.y * GRID1D), GRID1D - 1);
    int ca  = cya * GRID1D + cxa;
    int cxb = min((int)(p2.z * GRID1D), GRID1D - 1);
    int cyb = min((int)(p2.w * GRID1D), GRID1D - 1);
    int cb  = cyb * GRID1D + cxb;

    // two independent atomic->store chains (latency overlap)
    int pa = atomicAdd(&cur[seg * NCELL + ca], 1);
    int pb = atomicAdd(&cur[seg * NCELL + cb], 1);
    if (pa < SEGCAP)
        entries[(seg * NCELL + ca) * SEGCAP + pa] =
            make_float4(p2.x, p2.y, __int_as_float(2 * t), 0.0f);
    if (pb < SEGCAP)
        entries[(seg * NCELL + cb) * SEGCAP + pb] =
            make_float4(p2.z, p2.w, __int_as_float(2 * t + 1), 0.0f);
}

// ---------------- pass 2: per-cell cull + splat ----------------
struct GPair {   // two Gaussians interleaved for packed-f32 math (48 B)
    v2f p00, p01, nu, p11, nv, l2a;
};

__device__ inline v2f pair_term(const GPair& g, float X, float Y) {
    v2f u = g.p00 * X + g.p01 * Y + g.nu;
    v2f v = g.p11 * Y + g.nv;
    v2f w = g.l2a - u * u - v * v;
    v2f e;
    e.x = __builtin_amdgcn_exp2f(w.x);
    e.y = __builtin_amdgcn_exp2f(w.y);
    return e;
}

__global__ __launch_bounds__(128, 4)
void splat_kernel(const int* __restrict__ cur,
                  const float4* __restrict__ entries,
                  const float* __restrict__ alphas,
                  const float* __restrict__ means,
                  const float* __restrict__ rotations,
                  const float* __restrict__ scales,
                  float* __restrict__ out)
{
    __shared__ GPair  gp[NG / 2 + 4];
    __shared__ float2 px[PXCAP];
    __shared__ int    pidx[PXCAP];
    __shared__ int    nkept;

    int tid  = threadIdx.x;
    int cell = blockIdx.x;

    // segment counts + prefix (wave-uniform scalar loads)
    int pre[NSEG + 1];
    pre[0] = 0;
    #pragma unroll
    for (int s = 0; s < NSEG; ++s)
        pre[s + 1] = pre[s] + min(cur[s * NCELL + cell], SEGCAP);
    int total = min(pre[NSEG], PXCAP);
    if (total == 0) return;   // uniform across block

    if (tid == 0) nkept = 0;

    // stage this cell's pixels into LDS (dense list)
    for (int k = tid; k < total; k += 128) {
        int s = 0;
        while (k >= pre[s + 1]) ++s;
        float4 e = entries[(s * NCELL + cell) * SEGCAP + (k - pre[s])];
        px[k]   = make_float2(e.x, e.y);
        pidx[k] = __float_as_int(e.z);
    }
    __syncthreads();

    // cull 512 Gaussians against the cell box; compact survivors into LDS
    int cx = cell & (GRID1D - 1);
    int cy = cell >> 5;
    float bx0 = cx * (1.0f / GRID1D), bx1 = bx0 + (1.0f / GRID1D);
    float by0 = cy * (1.0f / GRID1D), by1 = by0 + (1.0f / GRID1D);

    for (int n = tid; n < NG; n += 128) {
        float rot = rotations[n];
        float sth, cth;
        sincosf(rot, &sth, &cth);
        float s0 = scales[2 * n + 0];
        float s1 = scales[2 * n + 1];
        float r00 = s0 * cth, r01 = -s1 * sth;
        float r10 = s0 * sth, r11 =  s1 * cth;
        float Ar = r00 * r00 + r01 * r01;
        float Br = r00 * r10 + r01 * r11;
        float Dr = r10 * r10 + r11 * r11;
        float det = Ar * Dr - Br * Br;
        float kc00 =  KSCALE * Dr / det;
        float kc01 = -KSCALE * Br / det;
        float p00 = sqrtf(kc00);
        float p01 = kc01 / p00;
        float p11 = sqrtf(KSCALE / Dr);
        float mx = means[2 * n + 0];
        float my = means[2 * n + 1];
        float nu = -(p00 * mx + p01 * my);
        float nv = -(p11 * my);
        float l2a = log2f(alphas[n]);

        float py0 = p01 * by0, py1 = p01 * by1;
        float umin = p00 * bx0 + fminf(py0, py1) + nu;
        float umax = p00 * bx1 + fmaxf(py0, py1) + nu;
        float vmin = p11 * by0 + nv;
        float vmax = p11 * by1 + nv;
        float du = (umin > 0.0f) ? umin : ((umax < 0.0f) ? umax : 0.0f);
        float dv = (vmin > 0.0f) ? vmin : ((vmax < 0.0f) ? vmax : 0.0f);
        float wmax = l2a - du * du - dv * dv;

        if (wmax > WCULL) {
            int slot = atomicAdd(&nkept, 1);
            int pr = slot >> 1, h = slot & 1;
            gp[pr].p00[h] = p00; gp[pr].p01[h] = p01; gp[pr].nu[h]  = nu;
            gp[pr].p11[h] = p11; gp[pr].nv[h]  = nv;  gp[pr].l2a[h] = l2a;
        }
    }
    __syncthreads();

    int nk = nkept;
    int nround = (nk + 7) & ~7;          // pad to multiple of 8 Gaussians
    if (tid < nround - nk) {
        int slot = nk + tid;
        int pr = slot >> 1, h = slot & 1;
        gp[pr].p00[h] = 0.0f; gp[pr].p01[h] = 0.0f; gp[pr].nu[h]  = 0.0f;
        gp[pr].p11[h] = 0.0f; gp[pr].nv[h]  = 0.0f; gp[pr].l2a[h] = -10000.0f;
    }
    __syncthreads();
    int npairs = nround >> 1;            // multiple of 4

    // 2 pixels per thread over the dense LDS list
    for (int p0 = tid; 2 * p0 < total; p0 += 128) {
        int ia = 2 * p0, ib = ia + 1;
        bool hasB = ib < total;
        float2 A = px[ia];
        float2 B = hasB ? px[ib] : A;
        v2f accA = {0.0f, 0.0f}, accB = {0.0f, 0.0f};

        for (int tp = 0; tp < npairs; tp += 4) {
            GPair g0 = gp[tp + 0];
            GPair g1 = gp[tp + 1];
            GPair g2 = gp[tp + 2];
            GPair g3 = gp[tp + 3];
            accA += pair_term(g0, A.x, A.y);  accB += pair_term(g0, B.x, B.y);
            accA += pair_term(g1, A.x, A.y);  accB += pair_term(g1, B.x, B.y);
            accA += pair_term(g2, A.x, A.y);  accB += pair_term(g2, B.x, B.y);
            accA += pair_term(g3, A.x, A.y);  accB += pair_term(g3, B.x, B.y);
        }

        out[pidx[ia]] = accA.x + accA.y;
        if (hasB) out[pidx[ib]] = accB.x + accB.y;
    }
}

extern "C" void kernel_launch(void* const* d_in, const int* in_sizes, int n_in,
                              void* d_out, int out_size, void* d_ws, size_t ws_size,
                              hipStream_t stream) {
    const float* x         = (const float*)d_in[0];
    const float* alphas    = (const float*)d_in[1];
    const float* means     = (const float*)d_in[2];
    const float* rotations = (const float*)d_in[3];
    const float* scales    = (const float*)d_in[4];
    float* out = (float*)d_out;

    char* ws = (char*)d_ws;
    int*    cur     = (int*)ws;
    float4* entries = (float4*)(ws + NSEG * NCELL * sizeof(int));

    hipMemsetAsync(cur, 0, NSEG * NCELL * sizeof(int), stream);
    bin_kernel<<<NPX / 512, 256, 0, stream>>>(x, cur, entries);
    splat_kernel<<<NCELL, 128, 0, stream>>>(cur, entries,
                                            alphas, means, rotations, scales, out);
}